// Round 4
// baseline (170.009 us; speedup 1.0000x reference)
//
#include <hip/hip_runtime.h>
#include <math.h>

#define N 16384
#define K 32
#define D 16
#define S 2048
#define E 500000
#define EPSF 1e-6f
#define B 256
#define GMAIN 256

// ---- workspace layout (float offsets) ----
#define OFF_Z      0                     // K*N (col-major softmax result)
#define OFF_CSPART (K*N)                 // 64*32 colsum partials
#define OFF_MPART  (OFF_CSPART + 2048)   // 64*1024 M partials
#define OFF_X      (OFF_MPART + 65536)   // N*D
#define OFF_XS     (OFF_X + N*D)         // S*D
#define OFF_BS     (OFF_XS + S*D)        // S
#define OFF_PD1    (OFF_BS + S)          // 256 pairwise partials
#define OFF_PD2    (OFF_PD1 + 256)       // 256 edge partials
#define OFF_SYNC   (OFF_PD2 + 256)       // ints: [ticket, cnt0, flag0, cnt1, flag1]

__device__ __forceinline__ void one_shot_barrier(int* cnt, int* flag, int nblk) {
    __syncthreads();
    __threadfence();  // make this block's writes visible agent-wide
    if (threadIdx.x == 0) {
        int t = __hip_atomic_fetch_add(cnt, 1, __ATOMIC_ACQ_REL,
                                       __HIP_MEMORY_SCOPE_AGENT);
        if (t == nblk - 1) {
            __hip_atomic_store(flag, 1, __ATOMIC_RELEASE,
                               __HIP_MEMORY_SCOPE_AGENT);
        } else {
            while (!__hip_atomic_load(flag, __ATOMIC_ACQUIRE,
                                      __HIP_MEMORY_SCOPE_AGENT))
                __builtin_amdgcn_s_sleep(2);
        }
    }
    __syncthreads();
}

__device__ __forceinline__ float block_reduce_sum(float v, float* sdata) {
    int tid = threadIdx.x;
    sdata[tid] = v;
    __syncthreads();
    for (int s = B >> 1; s > 0; s >>= 1) {
        if (tid < s) sdata[tid] += sdata[tid + s];
        __syncthreads();
    }
    return sdata[0];
}

// mode: 0 = all phases (cooperative, grid=256)
//       1 = phase AB (grid=128), 2 = phase C (grid=256), 3 = phase DE (grid=256)
__global__ __launch_bounds__(B) void fused(
    int mode,
    const float* __restrict__ beta, const float* __restrict__ A,
    const float* __restrict__ Zp, const float* __restrict__ Gate,
    const int* __restrict__ sample_idx, const int* __restrict__ sparse_i,
    const int* __restrict__ sparse_j, float* __restrict__ ws,
    float* __restrict__ out)
{
    const bool coop = (mode == 0);
    const bool doAB = (mode == 0 || mode == 1);
    const bool doC  = (mode == 0 || mode == 2);
    const bool doDE = (mode == 0 || mode == 3);
    __shared__ __align__(16) float sf[256 * 33 + 256];  // 34816 B
    __shared__ int sticket;
    int tid = threadIdx.x, bid = blockIdx.x;
    int* syncw = (int*)(ws + OFF_SYNC);

    // ========== Phase A (blocks 0..63): softmax cols + colsum partials ==========
    // ========== Phase B (blocks 64..127): Mpart from recomputed samples ==========
    if (doAB) {
        if (bid < 64) {
            int n = bid * B + tid;
            float z[K];
            float m = -1e30f;
#pragma unroll
            for (int k = 0; k < K; ++k) { z[k] = Zp[k * N + n]; m = fmaxf(m, z[k]); }
            float s = 0.f;
#pragma unroll
            for (int k = 0; k < K; ++k) { z[k] = expf(z[k] - m); s += z[k]; }
            float inv = 1.f / s;
#pragma unroll
            for (int k = 0; k < K; ++k) { z[k] *= inv; ws[OFF_Z + k * N + n] = z[k]; }
            float t[K];
            const float4* gp = reinterpret_cast<const float4*>(Gate + (size_t)n * K);
#pragma unroll
            for (int q = 0; q < K / 4; ++q) {
                float4 g = gp[q];
                t[4*q+0] = z[4*q+0] / (1.f + expf(-g.x));
                t[4*q+1] = z[4*q+1] / (1.f + expf(-g.y));
                t[4*q+2] = z[4*q+2] / (1.f + expf(-g.z));
                t[4*q+3] = z[4*q+3] / (1.f + expf(-g.w));
            }
#pragma unroll
            for (int k = 0; k < K; ++k) sf[tid * 33 + k] = t[k];
            __syncthreads();
            int kk = tid & 31, rg = tid >> 5;
            float acc = 0.f;
#pragma unroll
            for (int r = 0; r < 32; ++r) acc += sf[(rg * 32 + r) * 33 + kk];
            sf[256 * 33 + rg * 32 + kk] = acc;
            __syncthreads();
            if (rg == 0) {
                float tot = 0.f;
#pragma unroll
                for (int g2 = 0; g2 < 8; ++g2) tot += sf[256 * 33 + g2 * 32 + kk];
                ws[OFF_CSPART + bid * 32 + kk] = tot;
            }
        } else if (bid < 128) {
            // 32 samples per block, 8 threads per sample
            float* sZ = sf;           // 32*32
            float* sT = sf + 1024;    // 32*32
            int slot = tid >> 3, sub = tid & 7;
            int idx = sample_idx[(bid - 64) * 32 + slot];
            float za[4];
            float m = -1e30f;
#pragma unroll
            for (int q = 0; q < 4; ++q) {
                za[q] = Zp[(sub + 8 * q) * N + idx];
                m = fmaxf(m, za[q]);
            }
#pragma unroll
            for (int off = 1; off < 8; off <<= 1) m = fmaxf(m, __shfl_xor(m, off, 8));
            float ssum = 0.f;
#pragma unroll
            for (int q = 0; q < 4; ++q) { za[q] = expf(za[q] - m); ssum += za[q]; }
#pragma unroll
            for (int off = 1; off < 8; off <<= 1) ssum += __shfl_xor(ssum, off, 8);
            float inv = 1.f / ssum;
#pragma unroll
            for (int q = 0; q < 4; ++q) {
                int a = sub + 8 * q;
                float zv = za[q] * inv;
                float g = Gate[(size_t)idx * K + a];
                sZ[slot * 32 + a] = zv;
                sT[slot * 32 + a] = zv / (1.f + expf(-g));
            }
            __syncthreads();
#pragma unroll
            for (int e4 = 0; e4 < 4; ++e4) {
                int ent = tid + e4 * B;
                int a = ent >> 5, b = ent & 31;
                float acc = 0.f;
#pragma unroll
                for (int sl = 0; sl < 32; ++sl) acc += sZ[sl * 32 + a] * sT[sl * 32 + b];
                ws[OFF_MPART + (size_t)(bid - 64) * 1024 + ent] = acc;
            }
        }
    }
    if (coop) one_shot_barrier(syncw + 1, syncw + 2, GMAIN);

    // ========== Phase C (all 256): redundant M+AZC in LDS; X slice; Xs slice ==========
    if (doC) {
        float* sM  = sf;          // 1024
        float* scs = sf + 1024;   // 32
        float* sA  = sf + 1056;   // 512
        float macc[4];
#pragma unroll
        for (int j = 0; j < 4; ++j) {
            int ent = tid + j * B;
            float acc = 0.f;
            for (int p = 0; p < 64; ++p) acc += ws[OFF_MPART + (size_t)p * 1024 + ent];
            macc[j] = acc;
        }
        if (tid < 32) {
            float cs = 0.f;
#pragma unroll
            for (int b2 = 0; b2 < 64; ++b2) cs += ws[OFF_CSPART + b2 * 32 + tid];
            scs[tid] = cs;
        }
        __syncthreads();
#pragma unroll
        for (int j = 0; j < 4; ++j) sM[tid + j * B] = macc[j] / scs[tid & 31];
        __syncthreads();
#pragma unroll
        for (int j = 0; j < 2; ++j) {
            int e = tid + j * B;
            int d = e >> 5, bb = e & 31;
            float a2 = 0.f;
#pragma unroll
            for (int a = 0; a < K; ++a) a2 += A[d * K + a] * sM[a * 32 + bb];
            sA[e] = a2;
        }
        __syncthreads();
        // X rows [bid*64, bid*64+64): thread -> (row = tid>>2, dq = tid&3)
        {
            int n = bid * 64 + (tid >> 2);
            int dq = tid & 3;
            float x0 = 0.f, x1 = 0.f, x2 = 0.f, x3 = 0.f;
#pragma unroll
            for (int k = 0; k < K; ++k) {
                float zk = ws[OFF_Z + k * N + n];
                x0 = fmaf(sA[(dq * 4 + 0) * 32 + k], zk, x0);
                x1 = fmaf(sA[(dq * 4 + 1) * 32 + k], zk, x1);
                x2 = fmaf(sA[(dq * 4 + 2) * 32 + k], zk, x2);
                x3 = fmaf(sA[(dq * 4 + 3) * 32 + k], zk, x3);
            }
            float4 o; o.x = x0; o.y = x1; o.z = x2; o.w = x3;
            *reinterpret_cast<float4*>(ws + OFF_X + (size_t)n * D + dq * 4) = o;
        }
        // Xs rows [bid*8, bid*8+8): slot = tid>>5, lanes 0..15 compute d
        {
            int sslot = bid * 8 + (tid >> 5);
            int lane = tid & 31;
            int idx = sample_idx[sslot];
            if (lane < 16) {
                float xv = 0.f;
#pragma unroll
                for (int k = 0; k < K; ++k)
                    xv = fmaf(sA[lane * 32 + k], ws[OFF_Z + k * N + idx], xv);
                ws[OFF_XS + (size_t)sslot * D + lane] = xv;
                if (lane == 0) ws[OFF_BS + sslot] = beta[idx];
            }
        }
    }
    if (coop) one_shot_barrier(syncw + 3, syncw + 4, GMAIN);

    // ========== Phase D (all 256): pairwise rows [bid*8,+8) + edge slice ==========
    // ========== Phase E: ticket last block -> final scalar ==========
    if (doDE) {
        float* sdata = sf;        // 256
        float* sXr = sf + 256;    // 8*16
        float* sbr = sf + 384;    // 8
        float accP = 0.f, accE = 0.f;
        int r0 = bid * 8;
        if (tid < 8 * D) {
            int r = tid >> 4, d = tid & 15;
            sXr[r * D + d] = ws[OFF_XS + (size_t)(r0 + r) * D + d];
            if (d == 0) sbr[r] = ws[OFF_BS + r0 + r];
        }
        __syncthreads();
        for (int t = tid; t < S; t += B) {
            const float4* xp = reinterpret_cast<const float4*>(ws + OFF_XS + (size_t)t * D);
            float xt[D];
#pragma unroll
            for (int q = 0; q < D / 4; ++q) {
                float4 v = xp[q];
                xt[4*q] = v.x; xt[4*q+1] = v.y; xt[4*q+2] = v.z; xt[4*q+3] = v.w;
            }
            float bt = ws[OFF_BS + t];
#pragma unroll
            for (int r = 0; r < 8; ++r) {
                float d2 = 0.f;
#pragma unroll
                for (int d = 0; d < D; ++d) {
                    float df = sXr[r * D + d] - xt[d] + EPSF;
                    d2 = fmaf(df, df, d2);
                }
                float v = expf(sbr[r] + bt - sqrtf(d2));
                accP += (r0 + r == t) ? 0.f : v;
            }
        }
        for (int e = bid * B + tid; e < E; e += GMAIN * B) {
            int i = sparse_i[e], j = sparse_j[e];
            const float4* xi = reinterpret_cast<const float4*>(ws + OFF_X + (size_t)i * D);
            const float4* xj = reinterpret_cast<const float4*>(ws + OFF_X + (size_t)j * D);
            float d2 = 0.f;
#pragma unroll
            for (int q = 0; q < D / 4; ++q) {
                float4 a4 = xi[q], b4 = xj[q];
                float df;
                df = a4.x - b4.x + EPSF; d2 = fmaf(df, df, d2);
                df = a4.y - b4.y + EPSF; d2 = fmaf(df, df, d2);
                df = a4.z - b4.z + EPSF; d2 = fmaf(df, df, d2);
                df = a4.w - b4.w + EPSF; d2 = fmaf(df, df, d2);
            }
            accE += beta[i] + beta[j] - sqrtf(d2);
        }
        __syncthreads();
        float totP = block_reduce_sum(accP, sdata);
        __syncthreads();
        float totE = block_reduce_sum(accE, sdata);
        if (tid == 0) { ws[OFF_PD1 + bid] = totP; ws[OFF_PD2 + bid] = totE; }

        if (tid == 0) {
            __threadfence();
            sticket = atomicAdd(syncw, 1);
        }
        __syncthreads();
        if (sticket == GMAIN - 1) {
            __threadfence();
            float s1 = block_reduce_sum(ws[OFF_PD1 + tid], sdata);
            __syncthreads();
            float s2 = block_reduce_sum(ws[OFF_PD2 + tid], sdata);
            if (tid == 0) {
                float e = expf(1.0f);
                out[0] = s2 - 0.5f * e * e * s1;
            }
        }
    }
}

extern "C" void kernel_launch(void* const* d_in, const int* in_sizes, int n_in,
                              void* d_out, int out_size, void* d_ws, size_t ws_size,
                              hipStream_t stream) {
    const float* beta = (const float*)d_in[0];
    const float* A    = (const float*)d_in[1];
    const float* Zp   = (const float*)d_in[2];
    const float* Gate = (const float*)d_in[3];
    const int* sample_idx = (const int*)d_in[4];
    const int* sparse_i   = (const int*)d_in[5];
    const int* sparse_j   = (const int*)d_in[6];
    float* ws  = (float*)d_ws;
    float* out = (float*)d_out;

    // zero barrier/ticket state each call (capture-safe async memset)
    hipMemsetAsync((char*)d_ws + (size_t)OFF_SYNC * 4, 0, 32, stream);

    // Capture-safe host queries (no stream ops, no allocation).
    int dev = 0;
    hipGetDevice(&dev);
    int coopAttr = 0;
    hipDeviceGetAttribute(&coopAttr, hipDeviceAttributeCooperativeLaunch, dev);
    int nCU = 0;
    hipDeviceGetAttribute(&nCU, hipDeviceAttributeMultiprocessorCount, dev);
    int occ = 0;
    hipOccupancyMaxActiveBlocksPerMultiprocessor(&occ, (const void*)fused, B, 0);

    bool useCoop = (coopAttr != 0) && (occ > 0) && ((long)occ * nCU >= GMAIN);
    if (useCoop) {
        int mode = 0;
        void* args[] = {
            (void*)&mode, (void*)&beta, (void*)&A, (void*)&Zp, (void*)&Gate,
            (void*)&sample_idx, (void*)&sparse_i, (void*)&sparse_j,
            (void*)&ws, (void*)&out
        };
        hipError_t err = hipLaunchCooperativeKernel((const void*)fused, dim3(GMAIN),
                                                    dim3(B), args, 0, stream);
        if (err == hipSuccess) return;
        // else fall through to the phase-sliced path (identical arithmetic)
    }
    fused<<<128,   B, 0, stream>>>(1, beta, A, Zp, Gate, sample_idx, sparse_i, sparse_j, ws, out);
    fused<<<GMAIN, B, 0, stream>>>(2, beta, A, Zp, Gate, sample_idx, sparse_i, sparse_j, ws, out);
    fused<<<GMAIN, B, 0, stream>>>(3, beta, A, Zp, Gate, sample_idx, sparse_i, sparse_j, ws, out);
}

// Round 5
// 67.176 us; speedup vs baseline: 2.5308x; 2.5308x over previous
//
#include <hip/hip_runtime.h>
#include <math.h>

#define N 16384
#define K 32
#define D 16
#define S 2048
#define E 500000
#define EPSF 1e-6f
#define B 256
#define GMAIN 256

// ---- workspace layout (float offsets) ----
#define OFF_Z      0                     // K*N (col-major softmax result)
#define OFF_CSPART (K*N)                 // 64*32 colsum partials
#define OFF_MPART  (OFF_CSPART + 2048)   // 64*1024 M partials
#define OFF_X      (OFF_MPART + 65536)   // N*D
#define OFF_XS     (OFF_X + N*D)         // S*D
#define OFF_BS     (OFF_XS + S*D)        // S
#define OFF_PD1    (OFF_BS + S)          // 256 pairwise partials
#define OFF_PD2    (OFF_PD1 + 256)       // 256 edge partials
#define OFF_SYNC   (OFF_PD2 + 256)       // int ticket

__device__ __forceinline__ float block_reduce_sum(float v, float* sdata) {
    int tid = threadIdx.x;
    sdata[tid] = v;
    __syncthreads();
    for (int s = B >> 1; s > 0; s >>= 1) {
        if (tid < s) sdata[tid] += sdata[tid + s];
        __syncthreads();
    }
    return sdata[0];
}

// mode: 1 = phase AB (grid=128), 2 = phase C (grid=256), 3 = phase DE (grid=256)
// Grid-wide data dependencies are synchronized by KERNEL BOUNDARIES (the
// cheapest cross-XCD barrier on MI355X: in-kernel grid barriers measured
// 50+ us each due to per-XCD L2 coherence fences; boundary ~10 us).
__global__ __launch_bounds__(B) void fused(
    int mode,
    const float* __restrict__ beta, const float* __restrict__ A,
    const float* __restrict__ Zp, const float* __restrict__ Gate,
    const int* __restrict__ sample_idx, const int* __restrict__ sparse_i,
    const int* __restrict__ sparse_j, float* __restrict__ ws,
    float* __restrict__ out)
{
    __shared__ __align__(16) float sf[256 * 33 + 256];  // 34816 B
    __shared__ int sticket;
    int tid = threadIdx.x, bid = blockIdx.x;
    int* syncw = (int*)(ws + OFF_SYNC);

    // ========== Phase A (blocks 0..63): softmax cols + colsum partials ==========
    // ========== Phase B (blocks 64..127): Mpart from recomputed samples ==========
    if (mode == 1) {
        if (bid == 0 && tid == 0) syncw[0] = 0;  // ticket for mode-3 (stream-ordered)
        if (bid < 64) {
            int n = bid * B + tid;
            float z[K];
            float m = -1e30f;
#pragma unroll
            for (int k = 0; k < K; ++k) { z[k] = Zp[k * N + n]; m = fmaxf(m, z[k]); }
            float s = 0.f;
#pragma unroll
            for (int k = 0; k < K; ++k) { z[k] = expf(z[k] - m); s += z[k]; }
            float inv = 1.f / s;
#pragma unroll
            for (int k = 0; k < K; ++k) { z[k] *= inv; ws[OFF_Z + k * N + n] = z[k]; }
            float t[K];
            const float4* gp = reinterpret_cast<const float4*>(Gate + (size_t)n * K);
#pragma unroll
            for (int q = 0; q < K / 4; ++q) {
                float4 g = gp[q];
                t[4*q+0] = z[4*q+0] / (1.f + expf(-g.x));
                t[4*q+1] = z[4*q+1] / (1.f + expf(-g.y));
                t[4*q+2] = z[4*q+2] / (1.f + expf(-g.z));
                t[4*q+3] = z[4*q+3] / (1.f + expf(-g.w));
            }
#pragma unroll
            for (int k = 0; k < K; ++k) sf[tid * 33 + k] = t[k];
            __syncthreads();
            int kk = tid & 31, rg = tid >> 5;
            float acc = 0.f;
#pragma unroll
            for (int r = 0; r < 32; ++r) acc += sf[(rg * 32 + r) * 33 + kk];
            sf[256 * 33 + rg * 32 + kk] = acc;
            __syncthreads();
            if (rg == 0) {
                float tot = 0.f;
#pragma unroll
                for (int g2 = 0; g2 < 8; ++g2) tot += sf[256 * 33 + g2 * 32 + kk];
                ws[OFF_CSPART + bid * 32 + kk] = tot;
            }
        } else {
            // 32 samples per block, 8 threads per sample
            float* sZ = sf;           // 32*32
            float* sT = sf + 1024;    // 32*32
            int slot = tid >> 3, sub = tid & 7;
            int idx = sample_idx[(bid - 64) * 32 + slot];
            float za[4];
            float m = -1e30f;
#pragma unroll
            for (int q = 0; q < 4; ++q) {
                za[q] = Zp[(sub + 8 * q) * N + idx];
                m = fmaxf(m, za[q]);
            }
#pragma unroll
            for (int off = 1; off < 8; off <<= 1) m = fmaxf(m, __shfl_xor(m, off, 8));
            float ssum = 0.f;
#pragma unroll
            for (int q = 0; q < 4; ++q) { za[q] = expf(za[q] - m); ssum += za[q]; }
#pragma unroll
            for (int off = 1; off < 8; off <<= 1) ssum += __shfl_xor(ssum, off, 8);
            float inv = 1.f / ssum;
#pragma unroll
            for (int q = 0; q < 4; ++q) {
                int a = sub + 8 * q;
                float zv = za[q] * inv;
                float g = Gate[(size_t)idx * K + a];
                sZ[slot * 32 + a] = zv;
                sT[slot * 32 + a] = zv / (1.f + expf(-g));
            }
            __syncthreads();
#pragma unroll
            for (int e4 = 0; e4 < 4; ++e4) {
                int ent = tid + e4 * B;
                int a = ent >> 5, b = ent & 31;
                float acc = 0.f;
#pragma unroll
                for (int sl = 0; sl < 32; ++sl) acc += sZ[sl * 32 + a] * sT[sl * 32 + b];
                ws[OFF_MPART + (size_t)(bid - 64) * 1024 + ent] = acc;
            }
        }
        return;
    }

    // ========== Phase C (all 256): redundant M+AZC in LDS; X slice; Xs slice ==========
    if (mode == 2) {
        float* sM  = sf;          // 1024
        float* scs = sf + 1024;   // 32
        float* sA  = sf + 1056;   // 512
        float macc[4];
#pragma unroll
        for (int j = 0; j < 4; ++j) {
            int ent = tid + j * B;
            float acc = 0.f;
            for (int p = 0; p < 64; ++p) acc += ws[OFF_MPART + (size_t)p * 1024 + ent];
            macc[j] = acc;
        }
        if (tid < 32) {
            float cs = 0.f;
#pragma unroll
            for (int b2 = 0; b2 < 64; ++b2) cs += ws[OFF_CSPART + b2 * 32 + tid];
            scs[tid] = cs;
        }
        __syncthreads();
#pragma unroll
        for (int j = 0; j < 4; ++j) sM[tid + j * B] = macc[j] / scs[tid & 31];
        __syncthreads();
#pragma unroll
        for (int j = 0; j < 2; ++j) {
            int e = tid + j * B;
            int d = e >> 5, bb = e & 31;
            float a2 = 0.f;
#pragma unroll
            for (int a = 0; a < K; ++a) a2 += A[d * K + a] * sM[a * 32 + bb];
            sA[e] = a2;
        }
        __syncthreads();
        // X rows [bid*64, bid*64+64): thread -> (row = tid>>2, dq = tid&3)
        {
            int n = bid * 64 + (tid >> 2);
            int dq = tid & 3;
            float x0 = 0.f, x1 = 0.f, x2 = 0.f, x3 = 0.f;
#pragma unroll
            for (int k = 0; k < K; ++k) {
                float zk = ws[OFF_Z + k * N + n];
                x0 = fmaf(sA[(dq * 4 + 0) * 32 + k], zk, x0);
                x1 = fmaf(sA[(dq * 4 + 1) * 32 + k], zk, x1);
                x2 = fmaf(sA[(dq * 4 + 2) * 32 + k], zk, x2);
                x3 = fmaf(sA[(dq * 4 + 3) * 32 + k], zk, x3);
            }
            float4 o; o.x = x0; o.y = x1; o.z = x2; o.w = x3;
            *reinterpret_cast<float4*>(ws + OFF_X + (size_t)n * D + dq * 4) = o;
        }
        // Xs rows [bid*8, bid*8+8): slot = tid>>5, lanes 0..15 compute d
        {
            int sslot = bid * 8 + (tid >> 5);
            int lane = tid & 31;
            int idx = sample_idx[sslot];
            if (lane < 16) {
                float xv = 0.f;
#pragma unroll
                for (int k = 0; k < K; ++k)
                    xv = fmaf(sA[lane * 32 + k], ws[OFF_Z + k * N + idx], xv);
                ws[OFF_XS + (size_t)sslot * D + lane] = xv;
                if (lane == 0) ws[OFF_BS + sslot] = beta[idx];
            }
        }
        return;
    }

    // ========== Phase D (all 256): pairwise rows [bid*8,+8) + edge slice ==========
    // ========== Phase E: ticket last block -> final scalar ==========
    {
        float* sdata = sf;        // 256
        float* sXr = sf + 256;    // 8*16
        float* sbr = sf + 384;    // 8
        float accP = 0.f, accE = 0.f;
        int r0 = bid * 8;
        if (tid < 8 * D) {
            int r = tid >> 4, d = tid & 15;
            sXr[r * D + d] = ws[OFF_XS + (size_t)(r0 + r) * D + d];
            if (d == 0) sbr[r] = ws[OFF_BS + r0 + r];
        }
        __syncthreads();
        for (int t = tid; t < S; t += B) {
            const float4* xp = reinterpret_cast<const float4*>(ws + OFF_XS + (size_t)t * D);
            float xt[D];
#pragma unroll
            for (int q = 0; q < D / 4; ++q) {
                float4 v = xp[q];
                xt[4*q] = v.x; xt[4*q+1] = v.y; xt[4*q+2] = v.z; xt[4*q+3] = v.w;
            }
            float bt = ws[OFF_BS + t];
#pragma unroll
            for (int r = 0; r < 8; ++r) {
                float d2 = 0.f;
#pragma unroll
                for (int d = 0; d < D; ++d) {
                    float df = sXr[r * D + d] - xt[d] + EPSF;
                    d2 = fmaf(df, df, d2);
                }
                float v = expf(sbr[r] + bt - sqrtf(d2));
                accP += (r0 + r == t) ? 0.f : v;
            }
        }
        for (int e = bid * B + tid; e < E; e += GMAIN * B) {
            int i = sparse_i[e], j = sparse_j[e];
            const float4* xi = reinterpret_cast<const float4*>(ws + OFF_X + (size_t)i * D);
            const float4* xj = reinterpret_cast<const float4*>(ws + OFF_X + (size_t)j * D);
            float d2 = 0.f;
#pragma unroll
            for (int q = 0; q < D / 4; ++q) {
                float4 a4 = xi[q], b4 = xj[q];
                float df;
                df = a4.x - b4.x + EPSF; d2 = fmaf(df, df, d2);
                df = a4.y - b4.y + EPSF; d2 = fmaf(df, df, d2);
                df = a4.z - b4.z + EPSF; d2 = fmaf(df, df, d2);
                df = a4.w - b4.w + EPSF; d2 = fmaf(df, df, d2);
            }
            accE += beta[i] + beta[j] - sqrtf(d2);
        }
        __syncthreads();
        float totP = block_reduce_sum(accP, sdata);
        __syncthreads();
        float totE = block_reduce_sum(accE, sdata);
        if (tid == 0) { ws[OFF_PD1 + bid] = totP; ws[OFF_PD2 + bid] = totE; }

        if (tid == 0) {
            __threadfence();  // release: make PD1/PD2 visible agent-wide
            sticket = atomicAdd(syncw, 1);
        }
        __syncthreads();
        if (sticket == GMAIN - 1) {
            __threadfence();  // acquire: see all other blocks' PD writes
            float s1 = block_reduce_sum(ws[OFF_PD1 + tid], sdata);
            __syncthreads();
            float s2 = block_reduce_sum(ws[OFF_PD2 + tid], sdata);
            if (tid == 0) {
                float e = expf(1.0f);
                out[0] = s2 - 0.5f * e * e * s1;
            }
        }
    }
}

extern "C" void kernel_launch(void* const* d_in, const int* in_sizes, int n_in,
                              void* d_out, int out_size, void* d_ws, size_t ws_size,
                              hipStream_t stream) {
    const float* beta = (const float*)d_in[0];
    const float* A    = (const float*)d_in[1];
    const float* Zp   = (const float*)d_in[2];
    const float* Gate = (const float*)d_in[3];
    const int* sample_idx = (const int*)d_in[4];
    const int* sparse_i   = (const int*)d_in[5];
    const int* sparse_j   = (const int*)d_in[6];
    float* ws  = (float*)d_ws;
    float* out = (float*)d_out;

    fused<<<128,   B, 0, stream>>>(1, beta, A, Zp, Gate, sample_idx, sparse_i, sparse_j, ws, out);
    fused<<<GMAIN, B, 0, stream>>>(2, beta, A, Zp, Gate, sample_idx, sparse_i, sparse_j, ws, out);
    fused<<<GMAIN, B, 0, stream>>>(3, beta, A, Zp, Gate, sample_idx, sparse_i, sparse_j, ws, out);
}